// Round 17
// baseline (716.147 us; speedup 1.0000x reference)
//
#include <hip/hip_runtime.h>
#include <hip/hip_fp16.h>
#include <cstddef>
#include <cstdint>

typedef _Float16 f16;
typedef _Float16 f16x8 __attribute__((ext_vector_type(8)));
typedef _Float16 f16x4 __attribute__((ext_vector_type(4)));
typedef float    f32x4 __attribute__((ext_vector_type(4)));

#define BK 64   // K-tile depth (fp16 elems); 2 MFMA k-steps per tile

// async 16B global->LDS (linear LDS dest = wave-uniform base + lane*16)
__device__ __forceinline__ void gload16(const void* g, void* lds) {
  __builtin_amdgcn_global_load_lds(
      (const __attribute__((address_space(1))) unsigned int*)g,
      (__attribute__((address_space(3))) unsigned int*)lds, 16, 0, 0);
}

// Stage an [R x 64] fp16 tile via global_load_lds. LDS row r holds global
// 8-elem slot s at slot s^(r&7) (rule-21 both-sides swizzle).
template<int R>
__device__ __forceinline__ void stage_f16(f16 (*buf)[BK], const f16* __restrict__ src,
                                          int ld, int w, int lane) {
#pragma unroll
  for (int i = 0; i < R / 32; i++) {
    const int grp  = w * (R / 32) + i;          // wave-uniform
    const int r    = grp * 8 + (lane >> 3);
    const int slot = (lane & 7) ^ (r & 7);
    gload16(src + (size_t)r * ld + slot * 8, &buf[grp * 8][0]);
  }
}

// Reg-staging for f32 sources (T14 issue-early / write-late).
template<int R>
struct RegStage {
  static constexpr int NV = (R == 128) ? 8 : 4;
  float4 v[NV];
  __device__ __forceinline__ void load(const float* __restrict__ src, int ld, int tid) {
    const int r = (R == 128) ? (tid >> 1) : (tid >> 2);
    const int h = (R == 128) ? (tid & 1) * 32 : (tid & 3) * 16;
    const float* p = src + (size_t)r * ld + h;
#pragma unroll
    for (int j = 0; j < NV; j++) v[j] = ((const float4*)p)[j];
  }
  __device__ __forceinline__ void write(f16 (*buf)[BK], int tid) {
    const int r = (R == 128) ? (tid >> 1) : (tid >> 2);
    const int h = (R == 128) ? (tid & 1) * 32 : (tid & 3) * 16;
#pragma unroll
    for (int g = 0; g < NV / 2; g++) {
      const float4 a = v[g * 2], b = v[g * 2 + 1];
      f16x8 o;
      o[0] = (f16)a.x; o[1] = (f16)a.y; o[2] = (f16)a.z; o[3] = (f16)a.w;
      o[4] = (f16)b.x; o[5] = (f16)b.y; o[6] = (f16)b.z; o[7] = (f16)b.w;
      const int slot = (h / 8 + g) ^ (r & 7);
      *(f16x8*)&buf[r][slot * 8] = o;
    }
  }
};

// ---------------------------------------------------------------------------
// TN GEMM, double-buffered (proven core): C = A@B^T (+bias[n]) (+relu).
// fp16 operands: global_load_lds. f32 operands: reg-stage + cvt.
// Chunked bijective XCD swizzle on (bx,by); requires nxy % 8 == 0.
// ---------------------------------------------------------------------------
template<int BMt, int BNt, typename TA, typename TB, bool BIAS, bool RELU, typename TC>
__global__ __launch_bounds__(256, 2)
void gemm_tn(const TA* __restrict__ A, int lda,
             const TB* __restrict__ B, int ldb,
             TC* __restrict__ C, int ldc,
             const float* __restrict__ bias, int K)
{
  constexpr int MF = BMt / 32;
  constexpr int NF = BNt / 32;
  __shared__ f16 As[2][BMt][BK];
  __shared__ f16 Bs[2][BNt][BK];
  const int tid  = threadIdx.x;
  const int lane = tid & 63;
  const int w    = tid >> 6;
  const int wr   = w >> 1, wc = w & 1;

  const int gx = gridDim.x, nxy = gx * gridDim.y;
  int lin = blockIdx.y * gx + blockIdx.x;
  lin = (lin & 7) * (nxy >> 3) + (lin >> 3);
  const int m0 = (lin % gx) * BMt;
  const int n0 = (lin / gx) * BNt;

  f32x4 acc[MF][NF] = {};
  RegStage<BMt> ra;   // dead when TA == f16
  RegStage<BNt> rb;   // dead when TB == f16

  auto stage_issue = [&](int buf, int k0) {
    if constexpr (sizeof(TA) == 2)
      stage_f16<BMt>(As[buf], (const f16*)A + (size_t)m0 * lda + k0, lda, w, lane);
    else
      ra.load((const float*)A + (size_t)m0 * lda + k0, lda, tid);
    if constexpr (sizeof(TB) == 2)
      stage_f16<BNt>(Bs[buf], (const f16*)B + (size_t)n0 * ldb + k0, ldb, w, lane);
    else
      rb.load((const float*)B + (size_t)n0 * ldb + k0, ldb, tid);
  };
  auto stage_write = [&](int buf) {
    if constexpr (sizeof(TA) == 4) ra.write(As[buf], tid);
    if constexpr (sizeof(TB) == 4) rb.write(Bs[buf], tid);
  };
  auto compute = [&](int buf) {
    const int fr = lane & 15, q = lane >> 4;
#pragma unroll
    for (int kk = 0; kk < 2; kk++) {
      f16x8 af[MF], bf[NF];
#pragma unroll
      for (int i = 0; i < MF; i++) {
        const int r = wr * (BMt / 2) + i * 16 + fr;
        const int slot = (kk * 4 + q) ^ (r & 7);
        af[i] = *(const f16x8*)&As[buf][r][slot * 8];
      }
#pragma unroll
      for (int j = 0; j < NF; j++) {
        const int r = wc * (BNt / 2) + j * 16 + fr;
        const int slot = (kk * 4 + q) ^ (r & 7);
        bf[j] = *(const f16x8*)&Bs[buf][r][slot * 8];
      }
#pragma unroll
      for (int i = 0; i < MF; i++)
#pragma unroll
        for (int j = 0; j < NF; j++)
          acc[i][j] = __builtin_amdgcn_mfma_f32_16x16x32_f16(af[i], bf[j], acc[i][j], 0, 0, 0);
    }
  };

  stage_issue(0, 0);
  stage_write(0);
  __syncthreads();

  const int KT = K / BK;
  for (int kt = 0; kt < KT; kt++) {
    const int cur = kt & 1, nxt = cur ^ 1;
    if (kt + 1 < KT) stage_issue(nxt, (kt + 1) * BK);
    compute(cur);
    if (kt + 1 < KT) stage_write(nxt);
    __syncthreads();
  }

  const int fr = lane & 15;
  const int rg = (lane >> 4) << 2;
#pragma unroll
  for (int i = 0; i < MF; i++) {
#pragma unroll
    for (int j = 0; j < NF; j++) {
      const int col = n0 + wc * (BNt / 2) + j * 16 + fr;
      float bv = 0.f;
      if constexpr (BIAS) bv = bias[col];
#pragma unroll
      for (int r = 0; r < 4; r++) {
        const int row = m0 + wr * (BMt / 2) + i * 16 + rg + r;
        float v = acc[i][j][r] + bv;
        if constexpr (RELU) v = fmaxf(v, 0.f);
        C[(size_t)row * ldc + col] = (TC)v;
      }
    }
  }
}

// f32 -> fp16 vector copy (8 elems/thread)
__global__ __launch_bounds__(256)
void copy_f32_f16(const float* __restrict__ in, f16* __restrict__ o)
{
  const size_t i = ((size_t)blockIdx.x * 256 + threadIdx.x) * 8;
  const float4 a = ((const float4*)(in + i))[0];
  const float4 b = ((const float4*)(in + i))[1];
  f16x8 v;
  v[0] = (f16)a.x; v[1] = (f16)a.y; v[2] = (f16)a.z; v[3] = (f16)a.w;
  v[4] = (f16)b.x; v[5] = (f16)b.y; v[6] = (f16)b.z; v[7] = (f16)b.w;
  *(f16x8*)(o + i) = v;
}

// merged U->Uh (blocks 0..511) and fcw->Fh (blocks 512..767); grid 512 = U only
__global__ __launch_bounds__(256)
void copy_uf(const float* __restrict__ U, const float* __restrict__ fcw,
             f16* __restrict__ Uh, f16* __restrict__ Fh)
{
  const bool isU = blockIdx.x < 512;
  const size_t base = (size_t)(isU ? blockIdx.x : blockIdx.x - 512) * 2048;
  const float* in = (isU ? U : fcw) + base;
  f16* o = (isU ? Uh : Fh) + base;
  const size_t i = (size_t)threadIdx.x * 8;
  const float4 a = ((const float4*)(in + i))[0];
  const float4 b = ((const float4*)(in + i))[1];
  f16x8 v;
  v[0] = (f16)a.x; v[1] = (f16)a.y; v[2] = (f16)a.z; v[3] = (f16)a.w;
  v[4] = (f16)b.x; v[5] = (f16)b.y; v[6] = (f16)b.z; v[7] = (f16)b.w;
  *(f16x8*)(o + i) = v;
}

// fcw row e (1024 f32) -> f16 at dst + e*4096 (dead Sb row-tails, stride 8KB).
// One row per block, 256 thr x 4 f32.
__global__ __launch_bounds__(256)
void copy_fcw_tails(const float* __restrict__ fcw, f16* __restrict__ dst)
{
  const int e = blockIdx.x;
  const float4 a = ((const float4*)(fcw + (size_t)e * 1024))[threadIdx.x];
  f16x4 o;
  o[0] = (f16)a.x; o[1] = (f16)a.y; o[2] = (f16)a.z; o[3] = (f16)a.w;
  *(f16x4*)(dst + (size_t)e * 4096 + threadIdx.x * 4) = o;
}

// bT[row] = dot(x1[row, :1024], bias)  (exact f32)
__global__ __launch_bounds__(256)
void bias_dot(const float* __restrict__ x1, const float* __restrict__ bias,
              float* __restrict__ bT)
{
  const int row  = blockIdx.x * 4 + (threadIdx.x >> 6);
  const int lane = threadIdx.x & 63;
  const float4* r = (const float4*)(x1 + (size_t)row * 1024);
  const float4* bb = (const float4*)bias;
  float acc = 0.f;
#pragma unroll
  for (int j = 0; j < 4; j++) {
    const float4 a = r[lane + j * 64];
    const float4 b = bb[lane + j * 64];
    acc += a.x * b.x + a.y * b.y + a.z * b.z + a.w * b.w;
  }
#pragma unroll
  for (int off = 32; off > 0; off >>= 1) acc += __shfl_xor(acc, off);
  if (lane == 0) bT[row] = acc;
}

// ---------------------------------------------------------------------------
// Wave-per-row softmax (R16-proven): one wave owns a full 2048-f32 row,
// all-register, shuffle-only. Writes P f16 packed into first 4KB of row.
// ---------------------------------------------------------------------------
__global__ __launch_bounds__(256)
void softmax_rows_w(float* __restrict__ S)
{
  const int row  = blockIdx.x * 4 + (threadIdx.x >> 6);
  const int lane = threadIdx.x & 63;
  float* rp = S + (size_t)row * 2048;
  const float4* pr = (const float4*)rp + lane;

  float f[32];
  float m = -3.4e38f;
#pragma unroll
  for (int k = 0; k < 8; k++) {
    const float4 v = pr[(size_t)k * 64];
    f[k * 4 + 0] = v.x; f[k * 4 + 1] = v.y; f[k * 4 + 2] = v.z; f[k * 4 + 3] = v.w;
    m = fmaxf(m, fmaxf(fmaxf(v.x, v.y), fmaxf(v.z, v.w)));
  }
#pragma unroll
  for (int off = 32; off > 0; off >>= 1) m = fmaxf(m, __shfl_xor(m, off));

  float s = 0.f;
#pragma unroll
  for (int i = 0; i < 32; i++) { f[i] = __expf(f[i] - m); s += f[i]; }
#pragma unroll
  for (int off = 32; off > 0; off >>= 1) s += __shfl_xor(s, off);
  const float inv = 1.f / s;

  f16* hp = (f16*)rp;
#pragma unroll
  for (int k = 0; k < 8; k++) {
    f16x4 o;
    o[0] = (f16)(f[k * 4 + 0] * inv); o[1] = (f16)(f[k * 4 + 1] * inv);
    o[2] = (f16)(f[k * 4 + 2] * inv); o[3] = (f16)(f[k * 4 + 3] * inv);
    *(f16x4*)(hp + 4 * lane + 256 * k) = o;
  }
}

// ---------------------------------------------------------------------------
extern "C" void kernel_launch(void* const* d_in, const int* in_sizes, int n_in,
                              void* d_out, int out_size, void* d_ws, size_t ws_size,
                              hipStream_t stream)
{
  const float* x1   = (const float*)d_in[0];
  const float* x2   = (const float*)d_in[1];
  const float* U    = (const float*)d_in[2];
  const float* bias = (const float*)d_in[3];
  const float* fcw  = (const float*)d_in[4];
  const float* fcb  = (const float*)d_in[5];
  float* out = (float*)d_out;

  const int S = 2048, D = 1024, E = 512, B = 8;
  const size_t MB = 1ull << 20;
  const size_t KB64 = 64 * 1024;

  // MODE2 (ws >= 23,134,208 — probe): W2 4 | bT 64K | Uh 2 | Sb 16 = 22.06 MiB
  // MODE1 (ws >= 21,037,056 — proven): W2 4 | bT 64K | Sb 16; Uh in Sb scratch.
  // MODE0: exact R10 champion fallback (17.06 MiB).
  const int MODE = (ws_size >= 4 * MB + KB64 + 2 * MB + 16 * MB) ? 2
                 : (ws_size >= 4 * MB + KB64 + 16 * MB)          ? 1 : 0;

  char* w = (char*)d_ws;
  f16*   W2   = (f16*)(w);
  f16*   W1Tf = (f16*)(w + 4 * MB);                       // MODE0 only
  float* bT   = MODE ? (float*)(w + 4 * MB) : (float*)(w + 6 * MB);
  float* Sb   = (MODE == 2) ? (float*)(w + 6 * MB + KB64)
              : MODE        ? (float*)(w + 4 * MB + KB64)
                            : (float*)(w + 6 * MB + KB64);
  f16*   Uh   = (MODE == 2) ? (f16*)(w + 4 * MB + KB64)   // dedicated
              : MODE        ? (f16*)((char*)Sb + 13 * MB) // Sb scratch
                            : (f16*)(w + 14 * MB + KB64);
  f16*   Fh   = (f16*)(w + 16 * MB + KB64);               // MODE0 only
  f16*   W1T  = MODE ? (f16*)Sb + 2048 : W1Tf;            // MODE1/2: tails r0-511
  // MODE1/2: Fh' in dead tails of Sb rows 512..1023 (post-softmax), ld 4096
  f16*   Fhp  = (f16*)Sb + (size_t)512 * 4096 + 2048;
  const int ldw1t = MODE ? 2 * S : S;

  // X2h_all overlays d_out exactly (row s of out[b] aliases row s of X2h[b]).
  // K4' writes out[b] rows only AFTER K2 consumed them (stream-ordered).
  f16* X2h = (f16*)d_out;

  copy_f32_f16<<<dim3(B * S * D / 2048), 256, 0, stream>>>(x2, X2h);
  bias_dot<<<dim3(B * S / 4), 256, 0, stream>>>(x1, bias, bT);
  if (MODE == 2)
    copy_uf<<<dim3(512), 256, 0, stream>>>(U, fcw, Uh, nullptr);
  else if (MODE == 0)
    copy_uf<<<dim3(768), 256, 0, stream>>>(U, fcw, Uh, Fh);

  for (int b = 0; b < B; b++) {
    const float* x1b = x1 + (size_t)b * S * D;
    const f16*   X2b = X2h + (size_t)b * S * D;

    if (MODE) {
      if (MODE == 1)  // recreate Uh in Sb scratch (destroyed by prev K2)
        copy_uf<<<dim3(512), 256, 0, stream>>>(U, fcw, Uh, nullptr);

      // K0: W2[t][d] = sum_e x1b[t,e] Uh[d,e]   grid (32,8)=256
      gemm_tn<64, 128, float, f16, false, false, f16><<<dim3(S / 64, D / 128), 256, 0, stream>>>(
          x1b, D, Uh, D, W2, D, nullptr, D);

      // K2 full, 128x128 tile: grid (16,16)=256, 1/CU
      gemm_tn<128, 128, f16, f16, true, false, float><<<dim3(S / 128, S / 128), 256, 0, stream>>>(
          X2b, D, W2, D, Sb, S, bT + (size_t)b * S, D);

      // softmax all 2048 rows (wave-per-row), grid 512
      softmax_rows_w<<<dim3(S / 4), 256, 0, stream>>>(Sb);

      // Fh' = (f16)fcw into dead tails of rows 512..1023 (safe: post-K2)
      copy_fcw_tails<<<dim3(E), 256, 0, stream>>>(fcw, Fhp);

      // W1T[e][t] into tails of rows 0..511: A=Fh' f16 gload (lda 4096),
      // B=x1b f32 reg-stage — values (f16)fcw identical to prior path
      gemm_tn<64, 64, f16, float, false, false, f16><<<dim3(E / 64, S / 64), 256, 0, stream>>>(
          Fhp, 2 * S, x1b, D, W1T, ldw1t, nullptr, D);

      // K4' full: out[b] = relu(P @ W1T^T + fcb)   grid (32,8)=256
      gemm_tn<64, 64, f16, f16, true, true, float><<<dim3(S / 64, E / 64), 256, 0, stream>>>(
          (const f16*)Sb, 2 * S, W1T, ldw1t, out + (size_t)b * S * E, E, fcb, S);
    } else {
      // === exact R10 champion fallback ===
      gemm_tn<64, 128, float, f16, false, false, f16><<<dim3(S / 64, D / 128), 256, 0, stream>>>(
          x1b, D, Uh, D, W2, D, nullptr, D);
      gemm_tn<64, 64, f16, float, false, false, f16><<<dim3(E / 64, S / 64), 256, 0, stream>>>(
          Fh, D, x1b, D, W1Tf, S, nullptr, D);
      for (int s0 = 0; s0 < S; s0 += 1024) {
        gemm_tn<64, 128, f16, f16, true, false, float><<<dim3(1024 / 64, S / 128), 256, 0, stream>>>(
            X2b + (size_t)s0 * D, D, W2, D, Sb, S, bT + (size_t)b * S, D);
        softmax_rows_w<<<dim3(1024 / 4), 256, 0, stream>>>(Sb);
        gemm_tn<64, 64, f16, f16, true, true, float><<<dim3(1024 / 64, E / 64), 256, 0, stream>>>(
            (const f16*)Sb, 2 * S, W1Tf, S, out + ((size_t)b * S + s0) * E, E, fcb, S);
      }
    }
  }
}

// Round 18
// 700.141 us; speedup vs baseline: 1.0229x; 1.0229x over previous
//
#include <hip/hip_runtime.h>
#include <hip/hip_fp16.h>
#include <cstddef>
#include <cstdint>

typedef _Float16 f16;
typedef _Float16 f16x8 __attribute__((ext_vector_type(8)));
typedef _Float16 f16x4 __attribute__((ext_vector_type(4)));
typedef float    f32x4 __attribute__((ext_vector_type(4)));

#define BK 64   // K-tile depth (fp16 elems); 2 MFMA k-steps per tile

// async 16B global->LDS (linear LDS dest = wave-uniform base + lane*16)
__device__ __forceinline__ void gload16(const void* g, void* lds) {
  __builtin_amdgcn_global_load_lds(
      (const __attribute__((address_space(1))) unsigned int*)g,
      (__attribute__((address_space(3))) unsigned int*)lds, 16, 0, 0);
}

// Stage an [R x 64] fp16 tile via global_load_lds. LDS row r holds global
// 8-elem slot s at slot s^(r&7) (rule-21 both-sides swizzle).
template<int R>
__device__ __forceinline__ void stage_f16(f16 (*buf)[BK], const f16* __restrict__ src,
                                          int ld, int w, int lane) {
#pragma unroll
  for (int i = 0; i < R / 32; i++) {
    const int grp  = w * (R / 32) + i;          // wave-uniform
    const int r    = grp * 8 + (lane >> 3);
    const int slot = (lane & 7) ^ (r & 7);
    gload16(src + (size_t)r * ld + slot * 8, &buf[grp * 8][0]);
  }
}

// Reg-staging for f32 sources (T14 issue-early / write-late).
template<int R>
struct RegStage {
  static constexpr int NV = (R == 128) ? 8 : 4;
  float4 v[NV];
  __device__ __forceinline__ void load(const float* __restrict__ src, int ld, int tid) {
    const int r = (R == 128) ? (tid >> 1) : (tid >> 2);
    const int h = (R == 128) ? (tid & 1) * 32 : (tid & 3) * 16;
    const float* p = src + (size_t)r * ld + h;
#pragma unroll
    for (int j = 0; j < NV; j++) v[j] = ((const float4*)p)[j];
  }
  __device__ __forceinline__ void write(f16 (*buf)[BK], int tid) {
    const int r = (R == 128) ? (tid >> 1) : (tid >> 2);
    const int h = (R == 128) ? (tid & 1) * 32 : (tid & 3) * 16;
#pragma unroll
    for (int g = 0; g < NV / 2; g++) {
      const float4 a = v[g * 2], b = v[g * 2 + 1];
      f16x8 o;
      o[0] = (f16)a.x; o[1] = (f16)a.y; o[2] = (f16)a.z; o[3] = (f16)a.w;
      o[4] = (f16)b.x; o[5] = (f16)b.y; o[6] = (f16)b.z; o[7] = (f16)b.w;
      const int slot = (h / 8 + g) ^ (r & 7);
      *(f16x8*)&buf[r][slot * 8] = o;
    }
  }
};

// ---------------------------------------------------------------------------
// TN GEMM, double-buffered (proven core): C = A@B^T (+bias[n]) (+relu).
// fp16 operands: global_load_lds. f32 operands: reg-stage + cvt.
// Chunked bijective XCD swizzle on (bx,by); requires nxy % 8 == 0.
// ---------------------------------------------------------------------------
template<int BMt, int BNt, typename TA, typename TB, bool BIAS, bool RELU, typename TC>
__global__ __launch_bounds__(256, 2)
void gemm_tn(const TA* __restrict__ A, int lda,
             const TB* __restrict__ B, int ldb,
             TC* __restrict__ C, int ldc,
             const float* __restrict__ bias, int K)
{
  constexpr int MF = BMt / 32;
  constexpr int NF = BNt / 32;
  __shared__ f16 As[2][BMt][BK];
  __shared__ f16 Bs[2][BNt][BK];
  const int tid  = threadIdx.x;
  const int lane = tid & 63;
  const int w    = tid >> 6;
  const int wr   = w >> 1, wc = w & 1;

  const int gx = gridDim.x, nxy = gx * gridDim.y;
  int lin = blockIdx.y * gx + blockIdx.x;
  lin = (lin & 7) * (nxy >> 3) + (lin >> 3);
  const int m0 = (lin % gx) * BMt;
  const int n0 = (lin / gx) * BNt;

  f32x4 acc[MF][NF] = {};
  RegStage<BMt> ra;   // dead when TA == f16
  RegStage<BNt> rb;   // dead when TB == f16

  auto stage_issue = [&](int buf, int k0) {
    if constexpr (sizeof(TA) == 2)
      stage_f16<BMt>(As[buf], (const f16*)A + (size_t)m0 * lda + k0, lda, w, lane);
    else
      ra.load((const float*)A + (size_t)m0 * lda + k0, lda, tid);
    if constexpr (sizeof(TB) == 2)
      stage_f16<BNt>(Bs[buf], (const f16*)B + (size_t)n0 * ldb + k0, ldb, w, lane);
    else
      rb.load((const float*)B + (size_t)n0 * ldb + k0, ldb, tid);
  };
  auto stage_write = [&](int buf) {
    if constexpr (sizeof(TA) == 4) ra.write(As[buf], tid);
    if constexpr (sizeof(TB) == 4) rb.write(Bs[buf], tid);
  };
  auto compute = [&](int buf) {
    const int fr = lane & 15, q = lane >> 4;
#pragma unroll
    for (int kk = 0; kk < 2; kk++) {
      f16x8 af[MF], bf[NF];
#pragma unroll
      for (int i = 0; i < MF; i++) {
        const int r = wr * (BMt / 2) + i * 16 + fr;
        const int slot = (kk * 4 + q) ^ (r & 7);
        af[i] = *(const f16x8*)&As[buf][r][slot * 8];
      }
#pragma unroll
      for (int j = 0; j < NF; j++) {
        const int r = wc * (BNt / 2) + j * 16 + fr;
        const int slot = (kk * 4 + q) ^ (r & 7);
        bf[j] = *(const f16x8*)&Bs[buf][r][slot * 8];
      }
#pragma unroll
      for (int i = 0; i < MF; i++)
#pragma unroll
        for (int j = 0; j < NF; j++)
          acc[i][j] = __builtin_amdgcn_mfma_f32_16x16x32_f16(af[i], bf[j], acc[i][j], 0, 0, 0);
    }
  };

  stage_issue(0, 0);
  stage_write(0);
  __syncthreads();

  const int KT = K / BK;
  for (int kt = 0; kt < KT; kt++) {
    const int cur = kt & 1, nxt = cur ^ 1;
    if (kt + 1 < KT) stage_issue(nxt, (kt + 1) * BK);
    compute(cur);
    if (kt + 1 < KT) stage_write(nxt);
    __syncthreads();
  }

  const int fr = lane & 15;
  const int rg = (lane >> 4) << 2;
#pragma unroll
  for (int i = 0; i < MF; i++) {
#pragma unroll
    for (int j = 0; j < NF; j++) {
      const int col = n0 + wc * (BNt / 2) + j * 16 + fr;
      float bv = 0.f;
      if constexpr (BIAS) bv = bias[col];
#pragma unroll
      for (int r = 0; r < 4; r++) {
        const int row = m0 + wr * (BMt / 2) + i * 16 + rg + r;
        float v = acc[i][j][r] + bv;
        if constexpr (RELU) v = fmaxf(v, 0.f);
        C[(size_t)row * ldc + col] = (TC)v;
      }
    }
  }
}

// merged head: blocks [0,8192) -> x2 f32->f16 copy; [8192,12288) -> bT rows
__global__ __launch_bounds__(256)
void prep_head(const float* __restrict__ x2, f16* __restrict__ X2h,
               const float* __restrict__ x1, const float* __restrict__ bias,
               float* __restrict__ bT)
{
  if (blockIdx.x < 8192) {
    const size_t i = ((size_t)blockIdx.x * 256 + threadIdx.x) * 8;
    const float4 a = ((const float4*)(x2 + i))[0];
    const float4 b = ((const float4*)(x2 + i))[1];
    f16x8 v;
    v[0] = (f16)a.x; v[1] = (f16)a.y; v[2] = (f16)a.z; v[3] = (f16)a.w;
    v[4] = (f16)b.x; v[5] = (f16)b.y; v[6] = (f16)b.z; v[7] = (f16)b.w;
    *(f16x8*)(X2h + i) = v;
  } else {
    const int row  = (blockIdx.x - 8192) * 4 + (threadIdx.x >> 6);
    const int lane = threadIdx.x & 63;
    const float4* r = (const float4*)(x1 + (size_t)row * 1024);
    const float4* bb = (const float4*)bias;
    float acc = 0.f;
#pragma unroll
    for (int j = 0; j < 4; j++) {
      const float4 a = r[lane + j * 64];
      const float4 b = bb[lane + j * 64];
      acc += a.x * b.x + a.y * b.y + a.z * b.z + a.w * b.w;
    }
#pragma unroll
    for (int off = 32; off > 0; off >>= 1) acc += __shfl_xor(acc, off);
    if (lane == 0) bT[row] = acc;
  }
}

// f32 -> fp16 vector copy (8 elems/thread)
__global__ __launch_bounds__(256)
void copy_f32_f16(const float* __restrict__ in, f16* __restrict__ o)
{
  const size_t i = ((size_t)blockIdx.x * 256 + threadIdx.x) * 8;
  const float4 a = ((const float4*)(in + i))[0];
  const float4 b = ((const float4*)(in + i))[1];
  f16x8 v;
  v[0] = (f16)a.x; v[1] = (f16)a.y; v[2] = (f16)a.z; v[3] = (f16)a.w;
  v[4] = (f16)b.x; v[5] = (f16)b.y; v[6] = (f16)b.z; v[7] = (f16)b.w;
  *(f16x8*)(o + i) = v;
}

// merged U->Uh (blocks 0..511) and fcw->Fh (blocks 512..767); grid 512 = U only
__global__ __launch_bounds__(256)
void copy_uf(const float* __restrict__ U, const float* __restrict__ fcw,
             f16* __restrict__ Uh, f16* __restrict__ Fh)
{
  const bool isU = blockIdx.x < 512;
  const size_t base = (size_t)(isU ? blockIdx.x : blockIdx.x - 512) * 2048;
  const float* in = (isU ? U : fcw) + base;
  f16* o = (isU ? Uh : Fh) + base;
  const size_t i = (size_t)threadIdx.x * 8;
  const float4 a = ((const float4*)(in + i))[0];
  const float4 b = ((const float4*)(in + i))[1];
  f16x8 v;
  v[0] = (f16)a.x; v[1] = (f16)a.y; v[2] = (f16)a.z; v[3] = (f16)a.w;
  v[4] = (f16)b.x; v[5] = (f16)b.y; v[6] = (f16)b.z; v[7] = (f16)b.w;
  *(f16x8*)(o + i) = v;
}

// ---------------------------------------------------------------------------
// Wave-per-row softmax: one wave owns a full 2048-f32 row (32 f32/lane,
// all-register, shuffle-only — no LDS, no barriers). Writes P f16 packed
// into the first 4KB of the row. Grid = rows/4, 256 thr (4 waves).
// ---------------------------------------------------------------------------
__global__ __launch_bounds__(256)
void softmax_rows_w(float* __restrict__ S)
{
  const int row  = blockIdx.x * 4 + (threadIdx.x >> 6);
  const int lane = threadIdx.x & 63;
  float* rp = S + (size_t)row * 2048;
  const float4* pr = (const float4*)rp + lane;   // f32 elems 4*lane + 256*k

  float f[32];
  float m = -3.4e38f;
#pragma unroll
  for (int k = 0; k < 8; k++) {
    const float4 v = pr[(size_t)k * 64];
    f[k * 4 + 0] = v.x; f[k * 4 + 1] = v.y; f[k * 4 + 2] = v.z; f[k * 4 + 3] = v.w;
    m = fmaxf(m, fmaxf(fmaxf(v.x, v.y), fmaxf(v.z, v.w)));
  }
#pragma unroll
  for (int off = 32; off > 0; off >>= 1) m = fmaxf(m, __shfl_xor(m, off));

  float s = 0.f;
#pragma unroll
  for (int i = 0; i < 32; i++) { f[i] = __expf(f[i] - m); s += f[i]; }
#pragma unroll
  for (int off = 32; off > 0; off >>= 1) s += __shfl_xor(s, off);
  const float inv = 1.f / s;

  // write f16x4 per k at elems 4*lane + 256*k (coalesced 512B per k)
  f16* hp = (f16*)rp;
#pragma unroll
  for (int k = 0; k < 8; k++) {
    f16x4 o;
    o[0] = (f16)(f[k * 4 + 0] * inv); o[1] = (f16)(f[k * 4 + 1] * inv);
    o[2] = (f16)(f[k * 4 + 2] * inv); o[3] = (f16)(f[k * 4 + 3] * inv);
    *(f16x4*)(hp + 4 * lane + 256 * k) = o;
  }
}

// ---------------------------------------------------------------------------
extern "C" void kernel_launch(void* const* d_in, const int* in_sizes, int n_in,
                              void* d_out, int out_size, void* d_ws, size_t ws_size,
                              hipStream_t stream)
{
  const float* x1   = (const float*)d_in[0];
  const float* x2   = (const float*)d_in[1];
  const float* U    = (const float*)d_in[2];
  const float* bias = (const float*)d_in[3];
  const float* fcw  = (const float*)d_in[4];
  const float* fcb  = (const float*)d_in[5];
  float* out = (float*)d_out;

  const int S = 2048, D = 1024, E = 512, B = 8;
  const size_t MB = 1ull << 20;
  const size_t KB64 = 64 * 1024;

  // MODE2 (ws >= 23,134,208 — probe): W2 4 | bT 64K | Uh 2 | Sb 16 = 22.06 MiB
  //   -> dedicated Uh, no per-batch copy_uf.
  // MODE1 (ws >= 21,037,056 — R15-proven): W2 4 | bT 64K | Sb 16; Uh in Sb
  //   scratch, recreated per batch (consumed by K0 before K2 overwrites).
  // MODE0: exact R10 champion fallback (17.06 MiB).
  const int MODE = (ws_size >= 4 * MB + KB64 + 2 * MB + 16 * MB) ? 2
                 : (ws_size >= 4 * MB + KB64 + 16 * MB)          ? 1 : 0;

  char* w = (char*)d_ws;
  f16*   W2   = (f16*)(w);
  f16*   W1Tf = (f16*)(w + 4 * MB);                       // MODE0 only
  float* bT   = MODE ? (float*)(w + 4 * MB) : (float*)(w + 6 * MB);
  float* Sb   = (MODE == 2) ? (float*)(w + 6 * MB + KB64)
              : MODE        ? (float*)(w + 4 * MB + KB64)
                            : (float*)(w + 6 * MB + KB64);
  f16*   Uh   = (MODE == 2) ? (f16*)(w + 4 * MB + KB64)   // dedicated
              : MODE        ? (f16*)((char*)Sb + 13 * MB) // Sb scratch
                            : (f16*)(w + 14 * MB + KB64);
  f16*   Fh   = (f16*)(w + 16 * MB + KB64);               // MODE0 only
  f16*   W1T  = MODE ? (f16*)Sb + 2048 : W1Tf;            // MODE1/2: row-tails
  const int ldw1t = MODE ? 2 * S : S;

  // X2h_all overlays d_out exactly (row s of out[b] aliases row s of X2h[b]).
  // K4' writes out[b] rows only AFTER K2 consumed them (stream-ordered).
  f16* X2h = (f16*)d_out;

  prep_head<<<dim3(8192 + 4096), 256, 0, stream>>>(x2, X2h, x1, bias, bT);
  if (MODE == 2)
    copy_uf<<<dim3(512), 256, 0, stream>>>(U, fcw, Uh, nullptr);
  else if (MODE == 0)
    copy_uf<<<dim3(768), 256, 0, stream>>>(U, fcw, Uh, Fh);

  for (int b = 0; b < B; b++) {
    const float* x1b = x1 + (size_t)b * S * D;
    const f16*   X2b = X2h + (size_t)b * S * D;

    if (MODE) {
      if (MODE == 1)  // recreate Uh in Sb scratch (destroyed by prev K2)
        copy_uf<<<dim3(512), 256, 0, stream>>>(U, fcw, Uh, nullptr);

      // K0: W2[t][d] = sum_e x1b[t,e] Uh[d,e]   grid (32,8)=256
      gemm_tn<64, 128, float, f16, false, false, f16><<<dim3(S / 64, D / 128), 256, 0, stream>>>(
          x1b, D, Uh, D, W2, D, nullptr, D);

      // K2 full, 128x128 tile: grid (16,16)=256, 1/CU
      gemm_tn<128, 128, f16, f16, true, false, float><<<dim3(S / 128, S / 128), 256, 0, stream>>>(
          X2b, D, W2, D, Sb, S, bT + (size_t)b * S, D);

      // softmax all 2048 rows (wave-per-row), grid 512
      softmax_rows_w<<<dim3(S / 4), 256, 0, stream>>>(Sb);

      // W1T[e][t] into Sb row-tails (dead after softmax), fcw f32 directly
      gemm_tn<64, 64, float, float, false, false, f16><<<dim3(E / 64, S / 64), 256, 0, stream>>>(
          fcw, D, x1b, D, W1T, ldw1t, nullptr, D);

      // K4' full: out[b] = relu(P @ W1T^T + fcb)   grid (32,8)=256
      gemm_tn<64, 64, f16, f16, true, true, float><<<dim3(S / 64, E / 64), 256, 0, stream>>>(
          (const f16*)Sb, 2 * S, W1T, ldw1t, out + (size_t)b * S * E, E, fcb, S);
    } else {
      // === exact R10 champion fallback ===
      gemm_tn<64, 128, float, f16, false, false, f16><<<dim3(S / 64, D / 128), 256, 0, stream>>>(
          x1b, D, Uh, D, W2, D, nullptr, D);
      gemm_tn<64, 64, f16, float, false, false, f16><<<dim3(E / 64, S / 64), 256, 0, stream>>>(
          Fh, D, x1b, D, W1Tf, S, nullptr, D);
      for (int s0 = 0; s0 < S; s0 += 1024) {
        gemm_tn<64, 128, f16, f16, true, false, float><<<dim3(1024 / 64, S / 128), 256, 0, stream>>>(
            X2b + (size_t)s0 * D, D, W2, D, Sb, S, bT + (size_t)b * S, D);
        softmax_rows_w<<<dim3(1024 / 4), 256, 0, stream>>>(Sb);
        gemm_tn<64, 64, f16, f16, true, true, float><<<dim3(1024 / 64, E / 64), 256, 0, stream>>>(
            (const f16*)Sb, 2 * S, W1Tf, S, out + ((size_t)b * S + s0) * E, E, fcb, S);
      }
    }
  }
}